// Round 1
// baseline (543.842 us; speedup 1.0000x reference)
//
#include <hip/hip_runtime.h>
#include <hip/hip_bf16.h>
#include <math.h>

// Problem constants
#define DIMC   256      // DIM
#define DI     512      // D_INNER
#define DS     16       // D_STATE
#define DTR    16       // DT_RANK
#define NX     48       // DT_RANK + 2*D_STATE
#define BATCH  8
#define LSEQ   1024     // H*W
#define MROWS  8192     // BATCH*LSEQ

// ---------------------------------------------------------------------------
// Kernel 1: LayerNorm over channel dim per (b,l) position.
// x layout (B, C, H, W) -> read strided; xn layout (M, C) row-major.
__global__ __launch_bounds__(64) void ln_kernel(const float* __restrict__ x,
                                                const float* __restrict__ gamma,
                                                const float* __restrict__ beta,
                                                float* __restrict__ xn) {
  int m = blockIdx.x;            // b*LSEQ + l
  int b = m >> 10, l = m & 1023;
  int tid = threadIdx.x;
  const float* xb = x + (size_t)b * (DIMC * LSEQ) + l;
  float v[4];
  float sum = 0.f, sq = 0.f;
#pragma unroll
  for (int i = 0; i < 4; ++i) {
    int c = tid + i * 64;
    v[i] = xb[(size_t)c * LSEQ];
    sum += v[i];
    sq += v[i] * v[i];
  }
#pragma unroll
  for (int off = 32; off > 0; off >>= 1) {
    sum += __shfl_xor(sum, off);
    sq  += __shfl_xor(sq, off);
  }
  float mean = sum * (1.f / DIMC);
  float var  = sq * (1.f / DIMC) - mean * mean;
  float rs   = rsqrtf(var + 1e-5f);
#pragma unroll
  for (int i = 0; i < 4; ++i) {
    int c = tid + i * 64;
    xn[(size_t)m * DIMC + c] = (v[i] - mean) * rs * gamma[c] + beta[c];
  }
}

// ---------------------------------------------------------------------------
// Generic f32 GEMM: C = A(MxK) * B(KxN). 64x64 tile, 4x4 per thread, KT=16.
// mode 0: plain write to C (row-major MxN).
// mode 1: out[b*C*L + n*L + l] = acc + X[same]  (transpose epilogue + residual)
#define TS 64
#define KT 16
__global__ __launch_bounds__(256) void gemm_f32(const float* __restrict__ A,
                                                const float* __restrict__ Bm,
                                                float* __restrict__ Cc,
                                                int M, int N, int K, int mode,
                                                const float* __restrict__ X) {
  __shared__ float As[KT][TS + 4];
  __shared__ float Bs[KT][TS + 4];
  int tid = threadIdx.x;
  int tx = tid & 15, ty = tid >> 4;
  int m0 = blockIdx.y * TS, n0 = blockIdx.x * TS;
  float acc[4][4] = {};

  for (int k0 = 0; k0 < K; k0 += KT) {
    {
      int mm = tid >> 2, kk = (tid & 3) << 2;
      const float* ap = A + (size_t)(m0 + mm) * K + k0 + kk;
      float4 v = *(const float4*)ap;
      As[kk + 0][mm] = v.x;
      As[kk + 1][mm] = v.y;
      As[kk + 2][mm] = v.z;
      As[kk + 3][mm] = v.w;
    }
    {
      int kk = tid >> 4, nn = (tid & 15) << 2;
      const float* bp = Bm + (size_t)(k0 + kk) * N + n0 + nn;
      float4 v = *(const float4*)bp;
      *(float4*)&Bs[kk][nn] = v;
    }
    __syncthreads();
#pragma unroll
    for (int kk = 0; kk < KT; ++kk) {
      float a[4], b[4];
      *(float4*)a = *(const float4*)&As[kk][ty * 4];
      *(float4*)b = *(const float4*)&Bs[kk][tx * 4];
#pragma unroll
      for (int i = 0; i < 4; ++i)
#pragma unroll
        for (int j = 0; j < 4; ++j) acc[i][j] = fmaf(a[i], b[j], acc[i][j]);
    }
    __syncthreads();
  }

  if (mode == 0) {
#pragma unroll
    for (int i = 0; i < 4; ++i) {
      int m = m0 + ty * 4 + i;
#pragma unroll
      for (int j = 0; j < 4; ++j) {
        int n = n0 + tx * 4 + j;
        Cc[(size_t)m * N + n] = acc[i][j];
      }
    }
  } else {
#pragma unroll
    for (int i = 0; i < 4; ++i) {
      int m = m0 + ty * 4 + i;
      int b = m >> 10, l = m & 1023;
#pragma unroll
      for (int j = 0; j < 4; ++j) {
        int n = n0 + tx * 4 + j;
        size_t o = (size_t)b * (DIMC * LSEQ) + (size_t)n * LSEQ + l;
        Cc[o] = acc[i][j] + X[o];
      }
    }
  }
}

// ---------------------------------------------------------------------------
// Kernel 3: depthwise causal conv (k=4) along l + bias + SiLU.
// u = xz[:, :512] with xz layout (M, 1024); u2 layout (M, 512).
__global__ __launch_bounds__(256) void conv_silu(const float* __restrict__ xz,
                                                 const float* __restrict__ conv_w,
                                                 const float* __restrict__ conv_b,
                                                 float* __restrict__ u2) {
  int idx = blockIdx.x * 256 + threadIdx.x;   // < MROWS*DI
  int c = idx & (DI - 1);
  int m = idx >> 9;
  int l = m & 1023;
  float acc = conv_b[c];
  const float* w = conv_w + c * 4;
#pragma unroll
  for (int k = 0; k < 4; ++k) {
    int lj = l - 3 + k;
    if (lj >= 0) acc = fmaf(xz[(size_t)(m - 3 + k) * 1024 + c], w[k], acc);
  }
  float sg = 1.f / (1.f + __expf(-acc));
  u2[idx] = acc * sg;
}

// ---------------------------------------------------------------------------
// Kernel 4: dbc = u2 (M x 512) @ W_xproj (512 x 48). 4 m-rows per block.
__global__ __launch_bounds__(256) void xproj_kernel(const float* __restrict__ u2,
                                                    const float* __restrict__ W_xproj,
                                                    float* __restrict__ dbc) {
  int tid = threadIdx.x;
  int j = tid & 63;
  int mi = tid >> 6;
  int m = blockIdx.x * 4 + mi;
  if (j >= NX) return;
  const float* ur = u2 + (size_t)m * DI;
  float acc = 0.f;
#pragma unroll 8
  for (int k = 0; k < DI; ++k) acc = fmaf(ur[k], W_xproj[k * NX + j], acc);
  dbc[(size_t)m * NX + j] = acc;
}

// ---------------------------------------------------------------------------
// Kernel 5: dt = softplus(dbc[:, :16] @ W_dt (16x512) + b_dt).
__global__ __launch_bounds__(256) void dt_kernel(const float* __restrict__ dbc,
                                                 const float* __restrict__ W_dt,
                                                 const float* __restrict__ b_dt,
                                                 float* __restrict__ dtv) {
  int m = blockIdx.x;
  int tid = threadIdx.x;
  __shared__ float r[DTR];
  if (tid < DTR) r[tid] = dbc[(size_t)m * NX + tid];
  __syncthreads();
  for (int d = tid; d < DI; d += 256) {
    float acc = b_dt[d];
#pragma unroll
    for (int k = 0; k < DTR; ++k) acc = fmaf(r[k], W_dt[k * DI + d], acc);
    float sp = (acc > 20.f) ? acc : log1pf(__expf(acc));
    dtv[(size_t)m * DI + d] = sp;
  }
}

// ---------------------------------------------------------------------------
// Kernel 6: selective scan. One thread per (d, s). Block = 16 d x 16 s.
// Grid: (8 batches, 32 d-blocks). Stages 64 time steps of dt/u/B/C in LDS.
__global__ __launch_bounds__(256) void scan_kernel(const float* __restrict__ dtv,
                                                   const float* __restrict__ u2,
                                                   const float* __restrict__ dbc,
                                                   const float* __restrict__ A_log,
                                                   float* __restrict__ y) {
  const int bb = blockIdx.x;       // batch
  const int dblk = blockIdx.y;     // d-block (16 d's)
  const int tid = threadIdx.x;
  const int di = tid >> 4;         // 0..15
  const int s  = tid & 15;         // 0..15
  const int d  = dblk * 16 + di;
  const float Ads = -__expf(A_log[d * DS + s]);
  float h = 0.f;

  __shared__ float sdt[64][16], su[64][16], sB[64][16], sC[64][16], sy[64][16];

  for (int t0 = 0; t0 < LSEQ; t0 += 64) {
#pragma unroll
    for (int q = 0; q < 4; ++q) {
      int lin = q * 256 + tid;      // 0..1023
      int tt = lin >> 4, dd = lin & 15;
      size_t m = (size_t)bb * LSEQ + t0 + tt;
      sdt[tt][dd] = dtv[m * DI + dblk * 16 + dd];
      su [tt][dd] = u2 [m * DI + dblk * 16 + dd];
      sB [tt][dd] = dbc[m * NX + DTR + dd];
      sC [tt][dd] = dbc[m * NX + DTR + DS + dd];
    }
    __syncthreads();
    for (int tt = 0; tt < 64; ++tt) {
      float dtt = sdt[tt][di];
      float uu  = su[tt][di];
      float Bv  = sB[tt][s];
      float Cv  = sC[tt][s];
      float da  = __expf(dtt * Ads);
      h = fmaf(da, h, dtt * uu * Bv);
      float v = h * Cv;
      v += __shfl_xor(v, 1);
      v += __shfl_xor(v, 2);
      v += __shfl_xor(v, 4);
      v += __shfl_xor(v, 8);
      if (s == 0) sy[tt][di] = v;
    }
    __syncthreads();
#pragma unroll
    for (int q = 0; q < 4; ++q) {
      int lin = q * 256 + tid;
      int tt = lin >> 4, dd = lin & 15;
      size_t m = (size_t)bb * LSEQ + t0 + tt;
      y[m * DI + dblk * 16 + dd] = sy[tt][dd];
    }
    __syncthreads();
  }
}

// ---------------------------------------------------------------------------
// Kernel 7: gate: y = (y + u2*D_skip) * silu(z), z = xz[:, 512:]. In-place on y.
__global__ __launch_bounds__(256) void gate_kernel(float* __restrict__ y,
                                                   const float* __restrict__ u2,
                                                   const float* __restrict__ xz,
                                                   const float* __restrict__ D_skip) {
  int idx = blockIdx.x * 256 + threadIdx.x;   // < MROWS*DI
  int d = idx & (DI - 1);
  int m = idx >> 9;
  float z = xz[(size_t)m * 1024 + DI + d];
  float sg = z / (1.f + __expf(-z));
  y[idx] = (y[idx] + u2[idx] * D_skip[d]) * sg;
}

// ---------------------------------------------------------------------------
extern "C" void kernel_launch(void* const* d_in, const int* in_sizes, int n_in,
                              void* d_out, int out_size, void* d_ws, size_t ws_size,
                              hipStream_t stream) {
  const float* x       = (const float*)d_in[0];
  const float* ln_g    = (const float*)d_in[1];
  const float* ln_b    = (const float*)d_in[2];
  const float* W_in    = (const float*)d_in[3];
  const float* conv_w  = (const float*)d_in[4];
  const float* conv_b  = (const float*)d_in[5];
  const float* W_xproj = (const float*)d_in[6];
  const float* W_dt    = (const float*)d_in[7];
  const float* b_dt    = (const float*)d_in[8];
  const float* A_log   = (const float*)d_in[9];
  const float* D_skip  = (const float*)d_in[10];
  const float* W_out   = (const float*)d_in[11];
  float* out = (float*)d_out;

  // Workspace layout (floats)
  float* ws  = (float*)d_ws;
  float* xn  = ws;                       // MROWS*DIMC     = 2,097,152
  float* xz  = xn + (size_t)MROWS * DIMC;   // MROWS*1024  = 8,388,608
  float* u2  = xz + (size_t)MROWS * 1024;   // MROWS*DI    = 4,194,304
  float* dbc = u2 + (size_t)MROWS * DI;     // MROWS*NX    =   393,216
  float* dtv = dbc + (size_t)MROWS * NX;    // MROWS*DI    = 4,194,304
  float* y   = dtv + (size_t)MROWS * DI;    // MROWS*DI    = 4,194,304

  // 1. LayerNorm
  ln_kernel<<<MROWS, 64, 0, stream>>>(x, ln_g, ln_b, xn);

  // 2. xz = xn @ W_in   (8192x256 @ 256x1024)
  dim3 g1(1024 / TS, MROWS / TS);
  gemm_f32<<<g1, 256, 0, stream>>>(xn, W_in, xz, MROWS, 1024, DIMC, 0, nullptr);

  // 3. depthwise conv + SiLU -> u2
  conv_silu<<<(MROWS * DI) / 256, 256, 0, stream>>>(xz, conv_w, conv_b, u2);

  // 4. dbc = u2 @ W_xproj
  xproj_kernel<<<MROWS / 4, 256, 0, stream>>>(u2, W_xproj, dbc);

  // 5. dt = softplus(dbc[:, :16] @ W_dt + b_dt)
  dt_kernel<<<MROWS, 256, 0, stream>>>(dbc, W_dt, b_dt, dtv);

  // 6. selective scan -> y
  dim3 gs(BATCH, DI / 16);
  scan_kernel<<<gs, 256, 0, stream>>>(dtv, u2, dbc, A_log, y);

  // 7. gate (in-place on y)
  gate_kernel<<<(MROWS * DI) / 256, 256, 0, stream>>>(y, u2, xz, D_skip);

  // 8. out = y @ W_out (transpose epilogue) + x
  dim3 g4(DIMC / TS, MROWS / TS);
  gemm_f32<<<g4, 256, 0, stream>>>(y, W_out, out, MROWS, DIMC, DI, 1, x);
}

// Round 2
// 385.432 us; speedup vs baseline: 1.4110x; 1.4110x over previous
//
#include <hip/hip_runtime.h>
#include <hip/hip_bf16.h>
#include <math.h>

// Problem constants
#define DIMC   256      // DIM
#define DI     512      // D_INNER
#define DS     16       // D_STATE
#define DTR    16       // DT_RANK
#define NX     48       // DT_RANK + 2*D_STATE
#define BATCH  8
#define LSEQ   1024     // H*W
#define MROWS  8192     // BATCH*LSEQ
#define CHUNK  64
#define NC     (LSEQ / CHUNK)   // 16 chunks

// ---------------------------------------------------------------------------
// Kernel 1: LayerNorm over channel dim per (b,l) position.
__global__ __launch_bounds__(64) void ln_kernel(const float* __restrict__ x,
                                                const float* __restrict__ gamma,
                                                const float* __restrict__ beta,
                                                float* __restrict__ xn) {
  int m = blockIdx.x;            // b*LSEQ + l
  int b = m >> 10, l = m & 1023;
  int tid = threadIdx.x;
  const float* xb = x + (size_t)b * (DIMC * LSEQ) + l;
  float v[4];
  float sum = 0.f, sq = 0.f;
#pragma unroll
  for (int i = 0; i < 4; ++i) {
    int c = tid + i * 64;
    v[i] = xb[(size_t)c * LSEQ];
    sum += v[i];
    sq += v[i] * v[i];
  }
#pragma unroll
  for (int off = 32; off > 0; off >>= 1) {
    sum += __shfl_xor(sum, off);
    sq  += __shfl_xor(sq, off);
  }
  float mean = sum * (1.f / DIMC);
  float var  = sq * (1.f / DIMC) - mean * mean;
  float rs   = rsqrtf(var + 1e-5f);
#pragma unroll
  for (int i = 0; i < 4; ++i) {
    int c = tid + i * 64;
    xn[(size_t)m * DIMC + c] = (v[i] - mean) * rs * gamma[c] + beta[c];
  }
}

// ---------------------------------------------------------------------------
// Generic f32 GEMM: C = A(MxK) * B(KxN). 64x64 tile, 4x4 per thread, KT=16.
#define TS 64
#define KT 16
__global__ __launch_bounds__(256) void gemm_f32(const float* __restrict__ A,
                                                const float* __restrict__ Bm,
                                                float* __restrict__ Cc,
                                                int M, int N, int K, int mode,
                                                const float* __restrict__ X) {
  __shared__ float As[KT][TS + 4];
  __shared__ float Bs[KT][TS + 4];
  int tid = threadIdx.x;
  int tx = tid & 15, ty = tid >> 4;
  int m0 = blockIdx.y * TS, n0 = blockIdx.x * TS;
  float acc[4][4] = {};

  for (int k0 = 0; k0 < K; k0 += KT) {
    {
      int mm = tid >> 2, kk = (tid & 3) << 2;
      const float* ap = A + (size_t)(m0 + mm) * K + k0 + kk;
      float4 v = *(const float4*)ap;
      As[kk + 0][mm] = v.x;
      As[kk + 1][mm] = v.y;
      As[kk + 2][mm] = v.z;
      As[kk + 3][mm] = v.w;
    }
    {
      int kk = tid >> 4, nn = (tid & 15) << 2;
      const float* bp = Bm + (size_t)(k0 + kk) * N + n0 + nn;
      float4 v = *(const float4*)bp;
      *(float4*)&Bs[kk][nn] = v;
    }
    __syncthreads();
#pragma unroll
    for (int kk = 0; kk < KT; ++kk) {
      float a[4], b[4];
      *(float4*)a = *(const float4*)&As[kk][ty * 4];
      *(float4*)b = *(const float4*)&Bs[kk][tx * 4];
#pragma unroll
      for (int i = 0; i < 4; ++i)
#pragma unroll
        for (int j = 0; j < 4; ++j) acc[i][j] = fmaf(a[i], b[j], acc[i][j]);
    }
    __syncthreads();
  }

  if (mode == 0) {
#pragma unroll
    for (int i = 0; i < 4; ++i) {
      int m = m0 + ty * 4 + i;
#pragma unroll
      for (int j = 0; j < 4; ++j) {
        int n = n0 + tx * 4 + j;
        Cc[(size_t)m * N + n] = acc[i][j];
      }
    }
  } else {
#pragma unroll
    for (int i = 0; i < 4; ++i) {
      int m = m0 + ty * 4 + i;
      int b = m >> 10, l = m & 1023;
#pragma unroll
      for (int j = 0; j < 4; ++j) {
        int n = n0 + tx * 4 + j;
        size_t o = (size_t)b * (DIMC * LSEQ) + (size_t)n * LSEQ + l;
        Cc[o] = acc[i][j] + X[o];
      }
    }
  }
}

// ---------------------------------------------------------------------------
// Kernel 3: depthwise causal conv (k=4) along l + bias + SiLU.
__global__ __launch_bounds__(256) void conv_silu(const float* __restrict__ xz,
                                                 const float* __restrict__ conv_w,
                                                 const float* __restrict__ conv_b,
                                                 float* __restrict__ u2) {
  int idx = blockIdx.x * 256 + threadIdx.x;   // < MROWS*DI
  int c = idx & (DI - 1);
  int m = idx >> 9;
  int l = m & 1023;
  float acc = conv_b[c];
  const float* w = conv_w + c * 4;
#pragma unroll
  for (int k = 0; k < 4; ++k) {
    int lj = l - 3 + k;
    if (lj >= 0) acc = fmaf(xz[(size_t)(m - 3 + k) * 1024 + c], w[k], acc);
  }
  float sg = 1.f / (1.f + __expf(-acc));
  u2[idx] = acc * sg;
}

// ---------------------------------------------------------------------------
// Kernel 4: dbc = u2 (M x 512) @ W_xproj (512 x 48). 4 m-rows per block.
__global__ __launch_bounds__(256) void xproj_kernel(const float* __restrict__ u2,
                                                    const float* __restrict__ W_xproj,
                                                    float* __restrict__ dbc) {
  int tid = threadIdx.x;
  int j = tid & 63;
  int mi = tid >> 6;
  int m = blockIdx.x * 4 + mi;
  if (j >= NX) return;
  const float* ur = u2 + (size_t)m * DI;
  float acc = 0.f;
#pragma unroll 8
  for (int k = 0; k < DI; ++k) acc = fmaf(ur[k], W_xproj[k * NX + j], acc);
  dbc[(size_t)m * NX + j] = acc;
}

// ---------------------------------------------------------------------------
// Kernel 5: dt = softplus(dbc[:, :16] @ W_dt (16x512) + b_dt).
__global__ __launch_bounds__(256) void dt_kernel(const float* __restrict__ dbc,
                                                 const float* __restrict__ W_dt,
                                                 const float* __restrict__ b_dt,
                                                 float* __restrict__ dtv) {
  int m = blockIdx.x;
  int tid = threadIdx.x;
  __shared__ float r[DTR];
  if (tid < DTR) r[tid] = dbc[(size_t)m * NX + tid];
  __syncthreads();
  for (int d = tid; d < DI; d += 256) {
    float acc = b_dt[d];
#pragma unroll
    for (int k = 0; k < DTR; ++k) acc = fmaf(r[k], W_dt[k * DI + d], acc);
    float sp = (acc > 20.f) ? acc : log1pf(__expf(acc));
    dtv[(size_t)m * DI + d] = sp;
  }
}

// ---------------------------------------------------------------------------
// Chunked selective scan. h_t = exp(dt_t*A)h_{t-1} + dt_t*B_t*u_t.
// Chunk transition collapses: prod exp(dt*A) = exp(A * sum dt).
//
// Pass 1: per (b, dblk, chunk): local scan from h=0 -> hend; also sum dt.
__global__ __launch_bounds__(256) void scan_pass1(const float* __restrict__ dtv,
                                                  const float* __restrict__ u2,
                                                  const float* __restrict__ dbc,
                                                  const float* __restrict__ A_log,
                                                  float* __restrict__ hend,
                                                  float* __restrict__ Ssum) {
  const int bb = blockIdx.x, dblk = blockIdx.y, cc = blockIdx.z;
  const int tid = threadIdx.x;
  const int di = tid >> 4, s = tid & 15;
  const int d = dblk * 16 + di;
  const float Ads = -__expf(A_log[d * DS + s]);

  __shared__ float sdt[CHUNK][16], su[CHUNK][16], sB[CHUNK][16];
  {
    const int t0 = cc * CHUNK;
#pragma unroll
    for (int q = 0; q < 4; ++q) {
      int lin = q * 256 + tid;      // 0..1023
      int tt = lin >> 4, dd = lin & 15;
      size_t m = (size_t)bb * LSEQ + t0 + tt;
      sdt[tt][dd] = dtv[m * DI + dblk * 16 + dd];
      su [tt][dd] = u2 [m * DI + dblk * 16 + dd];
      sB [tt][dd] = dbc[m * NX + DTR + dd];
    }
  }
  __syncthreads();
  float h = 0.f, dtsum = 0.f;
  for (int tt = 0; tt < CHUNK; ++tt) {
    float dtt = sdt[tt][di];
    h = fmaf(__expf(dtt * Ads), h, dtt * su[tt][di] * sB[tt][s]);
    dtsum += dtt;
  }
  size_t ci = ((size_t)(bb * NC + cc) * DI + d);
  hend[ci * DS + s] = h;
  if (s == 0) Ssum[ci] = dtsum;
}

// Pass 2: sequential combine over 16 chunks -> h_in per chunk.
__global__ __launch_bounds__(256) void scan_pass2(const float* __restrict__ A_log,
                                                  const float* __restrict__ hend,
                                                  const float* __restrict__ Ssum,
                                                  float* __restrict__ hin) {
  const int bb = blockIdx.x, dblk = blockIdx.y;
  const int tid = threadIdx.x;
  const int di = tid >> 4, s = tid & 15;
  const int d = dblk * 16 + di;
  const float Ads = -__expf(A_log[d * DS + s]);
  float h = 0.f;
  for (int cc = 0; cc < NC; ++cc) {
    size_t ci = ((size_t)(bb * NC + cc) * DI + d);
    hin[ci * DS + s] = h;
    h = fmaf(__expf(Ads * Ssum[ci]), h, hend[ci * DS + s]);
  }
}

// Pass 3: re-run each chunk from its true h_in, emitting y.
__global__ __launch_bounds__(256) void scan_pass3(const float* __restrict__ dtv,
                                                  const float* __restrict__ u2,
                                                  const float* __restrict__ dbc,
                                                  const float* __restrict__ A_log,
                                                  const float* __restrict__ hin,
                                                  float* __restrict__ y) {
  const int bb = blockIdx.x, dblk = blockIdx.y, cc = blockIdx.z;
  const int tid = threadIdx.x;
  const int di = tid >> 4, s = tid & 15;
  const int d = dblk * 16 + di;
  const float Ads = -__expf(A_log[d * DS + s]);

  __shared__ float sdt[CHUNK][16], su[CHUNK][16], sB[CHUNK][16], sC[CHUNK][16], sy[CHUNK][16];
  const int t0 = cc * CHUNK;
#pragma unroll
  for (int q = 0; q < 4; ++q) {
    int lin = q * 256 + tid;
    int tt = lin >> 4, dd = lin & 15;
    size_t m = (size_t)bb * LSEQ + t0 + tt;
    sdt[tt][dd] = dtv[m * DI + dblk * 16 + dd];
    su [tt][dd] = u2 [m * DI + dblk * 16 + dd];
    sB [tt][dd] = dbc[m * NX + DTR + dd];
    sC [tt][dd] = dbc[m * NX + DTR + DS + dd];
  }
  __syncthreads();
  float h = hin[((size_t)(bb * NC + cc) * DI + d) * DS + s];
  for (int tt = 0; tt < CHUNK; ++tt) {
    float dtt = sdt[tt][di];
    h = fmaf(__expf(dtt * Ads), h, dtt * su[tt][di] * sB[tt][s]);
    float v = h * sC[tt][s];
    v += __shfl_xor(v, 1);
    v += __shfl_xor(v, 2);
    v += __shfl_xor(v, 4);
    v += __shfl_xor(v, 8);
    if (s == 0) sy[tt][di] = v;
  }
  __syncthreads();
#pragma unroll
  for (int q = 0; q < 4; ++q) {
    int lin = q * 256 + tid;
    int tt = lin >> 4, dd = lin & 15;
    size_t m = (size_t)bb * LSEQ + t0 + tt;
    y[m * DI + dblk * 16 + dd] = sy[tt][dd];
  }
}

// ---------------------------------------------------------------------------
// Kernel 7: gate: y = (y + u2*D_skip) * silu(z). In-place on y.
__global__ __launch_bounds__(256) void gate_kernel(float* __restrict__ y,
                                                   const float* __restrict__ u2,
                                                   const float* __restrict__ xz,
                                                   const float* __restrict__ D_skip) {
  int idx = blockIdx.x * 256 + threadIdx.x;   // < MROWS*DI
  int d = idx & (DI - 1);
  int m = idx >> 9;
  float z = xz[(size_t)m * 1024 + DI + d];
  float sg = z / (1.f + __expf(-z));
  y[idx] = (y[idx] + u2[idx] * D_skip[d]) * sg;
}

// ---------------------------------------------------------------------------
extern "C" void kernel_launch(void* const* d_in, const int* in_sizes, int n_in,
                              void* d_out, int out_size, void* d_ws, size_t ws_size,
                              hipStream_t stream) {
  const float* x       = (const float*)d_in[0];
  const float* ln_g    = (const float*)d_in[1];
  const float* ln_b    = (const float*)d_in[2];
  const float* W_in    = (const float*)d_in[3];
  const float* conv_w  = (const float*)d_in[4];
  const float* conv_b  = (const float*)d_in[5];
  const float* W_xproj = (const float*)d_in[6];
  const float* W_dt    = (const float*)d_in[7];
  const float* b_dt    = (const float*)d_in[8];
  const float* A_log   = (const float*)d_in[9];
  const float* D_skip  = (const float*)d_in[10];
  const float* W_out   = (const float*)d_in[11];
  float* out = (float*)d_out;

  // Workspace layout (floats)
  float* ws   = (float*)d_ws;
  float* xn   = ws;                          // MROWS*DIMC   = 2,097,152
  float* xz   = xn  + (size_t)MROWS * DIMC;  // MROWS*1024   = 8,388,608
  float* u2   = xz  + (size_t)MROWS * 1024;  // MROWS*DI     = 4,194,304
  float* dbc  = u2  + (size_t)MROWS * DI;    // MROWS*NX     =   393,216
  float* dtv  = dbc + (size_t)MROWS * NX;    // MROWS*DI     = 4,194,304
  float* y    = dtv + (size_t)MROWS * DI;    // MROWS*DI     = 4,194,304
  float* hend = y   + (size_t)MROWS * DI;    // B*NC*DI*DS   = 1,048,576
  float* hin  = hend + (size_t)BATCH * NC * DI * DS;  // 1,048,576
  float* Ssum = hin  + (size_t)BATCH * NC * DI * DS;  // B*NC*DI = 65,536

  // 1. LayerNorm
  ln_kernel<<<MROWS, 64, 0, stream>>>(x, ln_g, ln_b, xn);

  // 2. xz = xn @ W_in   (8192x256 @ 256x1024)
  dim3 g1(1024 / TS, MROWS / TS);
  gemm_f32<<<g1, 256, 0, stream>>>(xn, W_in, xz, MROWS, 1024, DIMC, 0, nullptr);

  // 3. depthwise conv + SiLU -> u2
  conv_silu<<<(MROWS * DI) / 256, 256, 0, stream>>>(xz, conv_w, conv_b, u2);

  // 4. dbc = u2 @ W_xproj
  xproj_kernel<<<MROWS / 4, 256, 0, stream>>>(u2, W_xproj, dbc);

  // 5. dt = softplus(dbc[:, :16] @ W_dt + b_dt)
  dt_kernel<<<MROWS, 256, 0, stream>>>(dbc, W_dt, b_dt, dtv);

  // 6. chunked selective scan -> y
  dim3 gp13(BATCH, DI / 16, NC);
  dim3 gp2(BATCH, DI / 16);
  scan_pass1<<<gp13, 256, 0, stream>>>(dtv, u2, dbc, A_log, hend, Ssum);
  scan_pass2<<<gp2, 256, 0, stream>>>(A_log, hend, Ssum, hin);
  scan_pass3<<<gp13, 256, 0, stream>>>(dtv, u2, dbc, A_log, hin, y);

  // 7. gate (in-place on y)
  gate_kernel<<<(MROWS * DI) / 256, 256, 0, stream>>>(y, u2, xz, D_skip);

  // 8. out = y @ W_out (transpose epilogue) + x
  dim3 g4(DIMC / TS, MROWS / TS);
  gemm_f32<<<g4, 256, 0, stream>>>(y, W_out, out, MROWS, DIMC, DI, 1, x);
}

// Round 3
// 284.293 us; speedup vs baseline: 1.9130x; 1.3558x over previous
//
#include <hip/hip_runtime.h>
#include <hip/hip_bf16.h>
#include <math.h>

// Problem constants
#define DIMC   256      // DIM
#define DI     512      // D_INNER
#define DS     16       // D_STATE
#define DTR    16       // DT_RANK
#define NX     48       // DT_RANK + 2*D_STATE
#define BATCH  8
#define LSEQ   1024     // H*W
#define MROWS  8192     // BATCH*LSEQ
#define CHUNK  64
#define NC     (LSEQ / CHUNK)   // 16 chunks

typedef __attribute__((ext_vector_type(8))) short short8;
typedef __attribute__((ext_vector_type(4))) float f32x4;

__device__ __forceinline__ unsigned short f2bf(float v) {
  __hip_bfloat16 h = __float2bfloat16(v);
  return *reinterpret_cast<unsigned short*>(&h);
}

// Sum across the 16-lane group (lanes grouped by lane&15) using DPP only.
// After quad sums (xor1,xor2), row_half_mirror (lane^7) picks the other quad,
// row_mirror (lane^15) picks the other half-row. All VALU, zero DS ops.
__device__ __forceinline__ float dpp_sum16(float v) {
  float t;
  t = __int_as_float(__builtin_amdgcn_mov_dpp(__float_as_int(v), 0xB1,  0xF, 0xF, true)); v += t; // quad_perm [1,0,3,2]  = ^1
  t = __int_as_float(__builtin_amdgcn_mov_dpp(__float_as_int(v), 0x4E,  0xF, 0xF, true)); v += t; // quad_perm [2,3,0,1]  = ^2
  t = __int_as_float(__builtin_amdgcn_mov_dpp(__float_as_int(v), 0x141, 0xF, 0xF, true)); v += t; // row_half_mirror (^7)
  t = __int_as_float(__builtin_amdgcn_mov_dpp(__float_as_int(v), 0x140, 0xF, 0xF, true)); v += t; // row_mirror      (^15)
  return v;
}

// ---------------------------------------------------------------------------
// Kernel 0: weight prep: Wt[n][k] = bf16(W[k][n]).  Grid (N/32, K/32), 256 thr.
__global__ __launch_bounds__(256) void wprep(const float* __restrict__ W,
                                             unsigned short* __restrict__ Wt,
                                             int K, int N) {
  __shared__ float t[32][33];
  int n0 = blockIdx.x * 32, k0 = blockIdx.y * 32;
  int tx = threadIdx.x & 31, ty = threadIdx.x >> 5;   // ty 0..7
  for (int i = ty; i < 32; i += 8) t[i][tx] = W[(size_t)(k0 + i) * N + n0 + tx];
  __syncthreads();
  for (int i = ty; i < 32; i += 8)
    Wt[(size_t)(n0 + i) * K + k0 + tx] = f2bf(t[tx][i]);
}

// ---------------------------------------------------------------------------
// Kernel 1: LayerNorm over channel dim per (b,l); emits bf16 activations.
__global__ __launch_bounds__(64) void ln_kernel(const float* __restrict__ x,
                                                const float* __restrict__ gamma,
                                                const float* __restrict__ beta,
                                                unsigned short* __restrict__ xnb) {
  int m = blockIdx.x;            // b*LSEQ + l
  int b = m >> 10, l = m & 1023;
  int tid = threadIdx.x;
  const float* xb = x + (size_t)b * (DIMC * LSEQ) + l;
  float v[4];
  float sum = 0.f, sq = 0.f;
#pragma unroll
  for (int i = 0; i < 4; ++i) {
    int c = tid + i * 64;
    v[i] = xb[(size_t)c * LSEQ];
    sum += v[i];
    sq += v[i] * v[i];
  }
#pragma unroll
  for (int off = 32; off > 0; off >>= 1) {
    sum += __shfl_xor(sum, off);
    sq  += __shfl_xor(sq, off);
  }
  float mean = sum * (1.f / DIMC);
  float var  = sq * (1.f / DIMC) - mean * mean;
  float rs   = rsqrtf(var + 1e-5f);
#pragma unroll
  for (int i = 0; i < 4; ++i) {
    int c = tid + i * 64;
    xnb[(size_t)m * DIMC + c] = f2bf((v[i] - mean) * rs * gamma[c] + beta[c]);
  }
}

// ---------------------------------------------------------------------------
// bf16 MFMA GEMM: C(f32) = A(bf16 [M][K]) * Bt(bf16 [N][K])^T.
// Tile: 128(M) x 64(N), BK=32. 4 waves as 2x2, each wave 64x32 via 4x2 mfma
// 16x16x32 accumulators.
// mode 0: C row-major [M][N].
// mode 1: out[b*DIMC*LSEQ + n*LSEQ + l] = acc + X[same]  (float4 stores).
#define GTM 128
#define GTN 64
#define GBK 32
__global__ __launch_bounds__(256) void gemm_bf16(const unsigned short* __restrict__ A,
                                                 const unsigned short* __restrict__ Bt,
                                                 float* __restrict__ C,
                                                 int M, int N, int K, int mode,
                                                 const float* __restrict__ X) {
  __shared__ unsigned short As[GTM][GBK];
  __shared__ unsigned short Bs[GTN][GBK];
  const int tid = threadIdx.x;
  const int lane = tid & 63, wave = tid >> 6;
  const int wm = wave >> 1, wn = wave & 1;
  const int quad = lane >> 4, l16 = lane & 15;
  const int m0 = blockIdx.y * GTM, n0 = blockIdx.x * GTN;

  f32x4 acc[4][2];
#pragma unroll
  for (int i = 0; i < 4; ++i)
#pragma unroll
    for (int j = 0; j < 2; ++j) acc[i][j] = (f32x4){0.f, 0.f, 0.f, 0.f};

  for (int k0 = 0; k0 < K; k0 += GBK) {
    // Stage A tile: 128x32 bf16 = 512 16B chunks, 2 per thread.
#pragma unroll
    for (int q = 0; q < 2; ++q) {
      int id = q * 256 + tid;
      int row = id >> 2, c = id & 3;
      uint4 v = *(const uint4*)(A + (size_t)(m0 + row) * K + k0 + c * 8);
      *(uint4*)&As[row][c * 8] = v;
    }
    // Stage B tile: 64x32 bf16 = 256 chunks, 1 per thread.
    {
      int row = tid >> 2, c = tid & 3;
      uint4 v = *(const uint4*)(Bt + (size_t)(n0 + row) * K + k0 + c * 8);
      *(uint4*)&Bs[row][c * 8] = v;
    }
    __syncthreads();
    short8 af[4], bfrag[2];
#pragma unroll
    for (int i = 0; i < 4; ++i)
      af[i] = *(const short8*)&As[wm * 64 + i * 16 + l16][quad * 8];
#pragma unroll
    for (int j = 0; j < 2; ++j)
      bfrag[j] = *(const short8*)&Bs[wn * 32 + j * 16 + l16][quad * 8];
#pragma unroll
    for (int i = 0; i < 4; ++i)
#pragma unroll
      for (int j = 0; j < 2; ++j)
        acc[i][j] = __builtin_amdgcn_mfma_f32_16x16x32_bf16(af[i], bfrag[j], acc[i][j], 0, 0, 0);
    __syncthreads();
  }

  if (mode == 0) {
#pragma unroll
    for (int i = 0; i < 4; ++i) {
      int rowb = wm * 64 + i * 16 + quad * 4;
#pragma unroll
      for (int j = 0; j < 2; ++j) {
        int n = n0 + wn * 32 + j * 16 + l16;
#pragma unroll
        for (int r = 0; r < 4; ++r)
          C[(size_t)(m0 + rowb + r) * N + n] = acc[i][j][r];
      }
    }
  } else {
#pragma unroll
    for (int i = 0; i < 4; ++i) {
      int m = m0 + wm * 64 + i * 16 + quad * 4;   // 4 consecutive rows = 4 consecutive l
      int b = m >> 10, l = m & 1023;
#pragma unroll
      for (int j = 0; j < 2; ++j) {
        int n = n0 + wn * 32 + j * 16 + l16;
        size_t o = (size_t)b * (DIMC * LSEQ) + (size_t)n * LSEQ + l;
        f32x4 xv = *(const f32x4*)(X + o);
        f32x4 rv = acc[i][j] + xv;
        *(f32x4*)(C + o) = rv;
      }
    }
  }
}

// ---------------------------------------------------------------------------
// Kernel 3: depthwise causal conv (k=4) along l + bias + SiLU.
__global__ __launch_bounds__(256) void conv_silu(const float* __restrict__ xz,
                                                 const float* __restrict__ conv_w,
                                                 const float* __restrict__ conv_b,
                                                 float* __restrict__ u2) {
  int idx = blockIdx.x * 256 + threadIdx.x;   // < MROWS*DI
  int c = idx & (DI - 1);
  int m = idx >> 9;
  int l = m & 1023;
  float acc = conv_b[c];
  const float* w = conv_w + c * 4;
#pragma unroll
  for (int k = 0; k < 4; ++k) {
    int lj = l - 3 + k;
    if (lj >= 0) acc = fmaf(xz[(size_t)(m - 3 + k) * 1024 + c], w[k], acc);
  }
  float sg = 1.f / (1.f + __expf(-acc));
  u2[idx] = acc * sg;
}

// ---------------------------------------------------------------------------
// Kernel 4: dbc = u2 (M x 512) @ W_xproj (512 x 48). 4 m-rows per block.
__global__ __launch_bounds__(256) void xproj_kernel(const float* __restrict__ u2,
                                                    const float* __restrict__ W_xproj,
                                                    float* __restrict__ dbc) {
  int tid = threadIdx.x;
  int j = tid & 63;
  int mi = tid >> 6;
  int m = blockIdx.x * 4 + mi;
  if (j >= NX) return;
  const float* ur = u2 + (size_t)m * DI;
  float acc = 0.f;
#pragma unroll 8
  for (int k = 0; k < DI; ++k) acc = fmaf(ur[k], W_xproj[k * NX + j], acc);
  dbc[(size_t)m * NX + j] = acc;
}

// ---------------------------------------------------------------------------
// Kernel 5: dt = softplus(dbc[:, :16] @ W_dt (16x512) + b_dt).
__global__ __launch_bounds__(256) void dt_kernel(const float* __restrict__ dbc,
                                                 const float* __restrict__ W_dt,
                                                 const float* __restrict__ b_dt,
                                                 float* __restrict__ dtv) {
  int m = blockIdx.x;
  int tid = threadIdx.x;
  __shared__ float r[DTR];
  if (tid < DTR) r[tid] = dbc[(size_t)m * NX + tid];
  __syncthreads();
  for (int d = tid; d < DI; d += 256) {
    float acc = b_dt[d];
#pragma unroll
    for (int k = 0; k < DTR; ++k) acc = fmaf(r[k], W_dt[k * DI + d], acc);
    float sp = (acc > 20.f) ? acc : log1pf(__expf(acc));
    dtv[(size_t)m * DI + d] = sp;
  }
}

// ---------------------------------------------------------------------------
// Chunked selective scan. h_t = exp(dt_t*A)h_{t-1} + dt_t*B_t*u_t.
// Pass 1: per (b, dblk, chunk): local scan from h=0 -> hend; also sum dt.
__global__ __launch_bounds__(256) void scan_pass1(const float* __restrict__ dtv,
                                                  const float* __restrict__ u2,
                                                  const float* __restrict__ dbc,
                                                  const float* __restrict__ A_log,
                                                  float* __restrict__ hend,
                                                  float* __restrict__ Ssum) {
  const int bb = blockIdx.x, dblk = blockIdx.y, cc = blockIdx.z;
  const int tid = threadIdx.x;
  const int di = tid >> 4, s = tid & 15;
  const int d = dblk * 16 + di;
  const float Ads = -__expf(A_log[d * DS + s]);

  __shared__ float sdt[CHUNK][16], su[CHUNK][16], sB[CHUNK][16];
  {
    const int t0 = cc * CHUNK;
#pragma unroll
    for (int q = 0; q < 4; ++q) {
      int lin = q * 256 + tid;      // 0..1023
      int tt = lin >> 4, dd = lin & 15;
      size_t m = (size_t)bb * LSEQ + t0 + tt;
      sdt[tt][dd] = dtv[m * DI + dblk * 16 + dd];
      su [tt][dd] = u2 [m * DI + dblk * 16 + dd];
      sB [tt][dd] = dbc[m * NX + DTR + dd];
    }
  }
  __syncthreads();
  float h = 0.f, dtsum = 0.f;
  for (int tt = 0; tt < CHUNK; ++tt) {
    float dtt = sdt[tt][di];
    h = fmaf(__expf(dtt * Ads), h, dtt * su[tt][di] * sB[tt][s]);
    dtsum += dtt;
  }
  size_t ci = ((size_t)(bb * NC + cc) * DI + d);
  hend[ci * DS + s] = h;
  if (s == 0) Ssum[ci] = dtsum;
}

// Pass 2: sequential combine over 16 chunks -> h_in per chunk.
__global__ __launch_bounds__(256) void scan_pass2(const float* __restrict__ A_log,
                                                  const float* __restrict__ hend,
                                                  const float* __restrict__ Ssum,
                                                  float* __restrict__ hin) {
  const int bb = blockIdx.x, dblk = blockIdx.y;
  const int tid = threadIdx.x;
  const int di = tid >> 4, s = tid & 15;
  const int d = dblk * 16 + di;
  const float Ads = -__expf(A_log[d * DS + s]);
  float h = 0.f;
  for (int cc = 0; cc < NC; ++cc) {
    size_t ci = ((size_t)(bb * NC + cc) * DI + d);
    hin[ci * DS + s] = h;
    h = fmaf(__expf(Ads * Ssum[ci]), h, hend[ci * DS + s]);
  }
}

// Pass 3: re-run each chunk from its true h_in, emitting y. DPP reduction.
__global__ __launch_bounds__(256) void scan_pass3(const float* __restrict__ dtv,
                                                  const float* __restrict__ u2,
                                                  const float* __restrict__ dbc,
                                                  const float* __restrict__ A_log,
                                                  const float* __restrict__ hin,
                                                  float* __restrict__ y) {
  const int bb = blockIdx.x, dblk = blockIdx.y, cc = blockIdx.z;
  const int tid = threadIdx.x;
  const int di = tid >> 4, s = tid & 15;
  const int d = dblk * 16 + di;
  const float Ads = -__expf(A_log[d * DS + s]);

  __shared__ float sdt[CHUNK][16], su[CHUNK][16], sB[CHUNK][16], sC[CHUNK][16], sy[CHUNK][16];
  const int t0 = cc * CHUNK;
#pragma unroll
  for (int q = 0; q < 4; ++q) {
    int lin = q * 256 + tid;
    int tt = lin >> 4, dd = lin & 15;
    size_t m = (size_t)bb * LSEQ + t0 + tt;
    sdt[tt][dd] = dtv[m * DI + dblk * 16 + dd];
    su [tt][dd] = u2 [m * DI + dblk * 16 + dd];
    sB [tt][dd] = dbc[m * NX + DTR + dd];
    sC [tt][dd] = dbc[m * NX + DTR + DS + dd];
  }
  __syncthreads();
  float h = hin[((size_t)(bb * NC + cc) * DI + d) * DS + s];
  for (int tt = 0; tt < CHUNK; ++tt) {
    float dtt = sdt[tt][di];
    h = fmaf(__expf(dtt * Ads), h, dtt * su[tt][di] * sB[tt][s]);
    float v = dpp_sum16(h * sC[tt][s]);
    if (s == 0) sy[tt][di] = v;
  }
  __syncthreads();
#pragma unroll
  for (int q = 0; q < 4; ++q) {
    int lin = q * 256 + tid;
    int tt = lin >> 4, dd = lin & 15;
    size_t m = (size_t)bb * LSEQ + t0 + tt;
    y[m * DI + dblk * 16 + dd] = sy[tt][dd];
  }
}

// ---------------------------------------------------------------------------
// Kernel 7: gate: yb = bf16((y + u2*D_skip) * silu(z)).
__global__ __launch_bounds__(256) void gate_kernel(const float* __restrict__ y,
                                                   const float* __restrict__ u2,
                                                   const float* __restrict__ xz,
                                                   const float* __restrict__ D_skip,
                                                   unsigned short* __restrict__ yb) {
  int idx = blockIdx.x * 256 + threadIdx.x;   // < MROWS*DI
  int d = idx & (DI - 1);
  int m = idx >> 9;
  float z = xz[(size_t)m * 1024 + DI + d];
  float sg = z / (1.f + __expf(-z));
  yb[idx] = f2bf((y[idx] + u2[idx] * D_skip[d]) * sg);
}

// ---------------------------------------------------------------------------
extern "C" void kernel_launch(void* const* d_in, const int* in_sizes, int n_in,
                              void* d_out, int out_size, void* d_ws, size_t ws_size,
                              hipStream_t stream) {
  const float* x       = (const float*)d_in[0];
  const float* ln_g    = (const float*)d_in[1];
  const float* ln_b    = (const float*)d_in[2];
  const float* W_in    = (const float*)d_in[3];
  const float* conv_w  = (const float*)d_in[4];
  const float* conv_b  = (const float*)d_in[5];
  const float* W_xproj = (const float*)d_in[6];
  const float* W_dt    = (const float*)d_in[7];
  const float* b_dt    = (const float*)d_in[8];
  const float* A_log   = (const float*)d_in[9];
  const float* D_skip  = (const float*)d_in[10];
  const float* W_out   = (const float*)d_in[11];
  float* out = (float*)d_out;

  // Workspace layout
  float* ws   = (float*)d_ws;
  float* xz   = ws;                          // 8,388,608 f
  float* u2   = xz  + (size_t)MROWS * 1024;  // 4,194,304 f
  float* dbc  = u2  + (size_t)MROWS * DI;    //   393,216 f
  float* dtv  = dbc + (size_t)MROWS * NX;    // 4,194,304 f
  float* y    = dtv + (size_t)MROWS * DI;    // 4,194,304 f
  float* hend = y   + (size_t)MROWS * DI;    // 1,048,576 f
  float* hin  = hend + (size_t)BATCH * NC * DI * DS;  // 1,048,576 f
  float* Ssum = hin  + (size_t)BATCH * NC * DI * DS;  //    65,536 f
  unsigned short* yb  = (unsigned short*)(Ssum + (size_t)BATCH * NC * DI); // 4,194,304 us
  unsigned short* xnb = yb;   // alias: xnb dead before yb is written
  unsigned short* Wib = yb + (size_t)MROWS * DI;      // 262,144 us
  unsigned short* Wob = Wib + (size_t)DIMC * 1024;    // 131,072 us

  // 0. weight prep (transpose + bf16 cast)
  wprep<<<dim3(1024 / 32, DIMC / 32), 256, 0, stream>>>(W_in, Wib, DIMC, 1024);
  wprep<<<dim3(DIMC / 32, DI / 32), 256, 0, stream>>>(W_out, Wob, DI, DIMC);

  // 1. LayerNorm -> bf16
  ln_kernel<<<MROWS, 64, 0, stream>>>(x, ln_g, ln_b, xnb);

  // 2. xz = xn @ W_in   (8192x1024x256, bf16 MFMA)
  gemm_bf16<<<dim3(1024 / GTN, MROWS / GTM), 256, 0, stream>>>(
      xnb, Wib, xz, MROWS, 1024, DIMC, 0, nullptr);

  // 3. depthwise conv + SiLU -> u2
  conv_silu<<<(MROWS * DI) / 256, 256, 0, stream>>>(xz, conv_w, conv_b, u2);

  // 4. dbc = u2 @ W_xproj
  xproj_kernel<<<MROWS / 4, 256, 0, stream>>>(u2, W_xproj, dbc);

  // 5. dt = softplus(dbc[:, :16] @ W_dt + b_dt)
  dt_kernel<<<MROWS, 256, 0, stream>>>(dbc, W_dt, b_dt, dtv);

  // 6. chunked selective scan -> y
  dim3 gp13(BATCH, DI / 16, NC);
  dim3 gp2(BATCH, DI / 16);
  scan_pass1<<<gp13, 256, 0, stream>>>(dtv, u2, dbc, A_log, hend, Ssum);
  scan_pass2<<<gp2, 256, 0, stream>>>(A_log, hend, Ssum, hin);
  scan_pass3<<<gp13, 256, 0, stream>>>(dtv, u2, dbc, A_log, hin, y);

  // 7. gate -> yb (bf16)
  gate_kernel<<<(MROWS * DI) / 256, 256, 0, stream>>>(y, u2, xz, D_skip, yb);

  // 8. out = yb @ W_out (transpose epilogue, +x residual)
  gemm_bf16<<<dim3(DIMC / GTN, MROWS / GTM), 256, 0, stream>>>(
      yb, Wob, out, MROWS, DIMC, DI, 1, x);
}

// Round 4
// 225.606 us; speedup vs baseline: 2.4106x; 1.2601x over previous
//
#include <hip/hip_runtime.h>
#include <hip/hip_bf16.h>
#include <math.h>

// Problem constants
#define DIMC   256      // DIM
#define DI     512      // D_INNER
#define DS     16       // D_STATE
#define DTR    16       // DT_RANK
#define NX     48       // DT_RANK + 2*D_STATE
#define BATCH  8
#define LSEQ   1024     // H*W
#define MROWS  8192     // BATCH*LSEQ
#define CHUNK  64
#define NC     (LSEQ / CHUNK)   // 16 chunks

typedef __attribute__((ext_vector_type(8))) short short8;
typedef __attribute__((ext_vector_type(4))) float f32x4;

__device__ __forceinline__ unsigned short f2bf(float v) {
  __hip_bfloat16 h = __float2bfloat16(v);
  return *reinterpret_cast<unsigned short*>(&h);
}

// Sum across the 16-lane group using DPP only (zero DS ops).
__device__ __forceinline__ float dpp_sum16(float v) {
  float t;
  t = __int_as_float(__builtin_amdgcn_mov_dpp(__float_as_int(v), 0xB1,  0xF, 0xF, true)); v += t; // ^1
  t = __int_as_float(__builtin_amdgcn_mov_dpp(__float_as_int(v), 0x4E,  0xF, 0xF, true)); v += t; // ^2
  t = __int_as_float(__builtin_amdgcn_mov_dpp(__float_as_int(v), 0x141, 0xF, 0xF, true)); v += t; // ^7 (row_half_mirror)
  t = __int_as_float(__builtin_amdgcn_mov_dpp(__float_as_int(v), 0x140, 0xF, 0xF, true)); v += t; // ^15 (row_mirror)
  return v;
}

// ---------------------------------------------------------------------------
// Weight prep: Wt[n][k] = bf16(W[k][n]).  Grid (N/32, K/32), 256 thr.
__global__ __launch_bounds__(256) void wprep(const float* __restrict__ W,
                                             unsigned short* __restrict__ Wt,
                                             int K, int N) {
  __shared__ float t[32][33];
  int n0 = blockIdx.x * 32, k0 = blockIdx.y * 32;
  int tx = threadIdx.x & 31, ty = threadIdx.x >> 5;
  for (int i = ty; i < 32; i += 8) t[i][tx] = W[(size_t)(k0 + i) * N + n0 + tx];
  __syncthreads();
  for (int i = ty; i < 32; i += 8)
    Wt[(size_t)(n0 + i) * K + k0 + tx] = f2bf(t[tx][i]);
}

// W_xproj (512x48) -> Wxpb [64][512] bf16, rows 48..63 zero.
__global__ __launch_bounds__(256) void wxprep(const float* __restrict__ W_xproj,
                                              unsigned short* __restrict__ Wxpb) {
  int idx = blockIdx.x * 256 + threadIdx.x;   // < 64*512
  int n = idx >> 9, k = idx & 511;
  Wxpb[idx] = (n < NX) ? f2bf(W_xproj[(size_t)k * NX + n]) : (unsigned short)0;
}

// W_dt (16x512) -> Wdtb [512][32] bf16, cols k>=16 zero.
__global__ __launch_bounds__(256) void wdtprep(const float* __restrict__ W_dt,
                                               unsigned short* __restrict__ Wdtb) {
  int idx = blockIdx.x * 256 + threadIdx.x;   // < 512*32
  int n = idx >> 5, k = idx & 31;
  Wdtb[idx] = (k < DTR) ? f2bf(W_dt[(size_t)k * DI + n]) : (unsigned short)0;
}

// ---------------------------------------------------------------------------
// LayerNorm, coalesced tile version. Block: 64 l x 256 c; grid (16, 8).
__global__ __launch_bounds__(256) void ln_kernel(const float* __restrict__ x,
                                                 const float* __restrict__ gamma,
                                                 const float* __restrict__ beta,
                                                 unsigned short* __restrict__ xnb) {
  __shared__ float sx[DIMC][67];   // pad 67 -> conflict-light
  __shared__ float smean[64], srs[64];
  const int b = blockIdx.y, l0 = blockIdx.x * 64;
  const int tid = threadIdx.x;
  {
    const int cbase = tid >> 2;          // 0..63
    const int lp = (tid & 3) * 16;       // 0,16,32,48
#pragma unroll
    for (int cg = 0; cg < 4; ++cg) {
      const int c = cg * 64 + cbase;
      const float* p = x + ((size_t)b * DIMC + c) * LSEQ + l0 + lp;
#pragma unroll
      for (int q = 0; q < 4; ++q) {
        float4 v = *(const float4*)(p + q * 4);
        sx[c][lp + q * 4 + 0] = v.x;
        sx[c][lp + q * 4 + 1] = v.y;
        sx[c][lp + q * 4 + 2] = v.z;
        sx[c][lp + q * 4 + 3] = v.w;
      }
    }
  }
  __syncthreads();
  {
    const int lane = tid & 63, w = tid >> 6;
    const int l = (w << 4) + (lane & 15);
    const int quad = lane >> 4;
    float sum = 0.f, sq = 0.f;
#pragma unroll 8
    for (int cc = 0; cc < 64; ++cc) {
      float v = sx[quad * 64 + cc][l];
      sum += v; sq += v * v;
    }
    sum += __shfl_xor(sum, 16); sq += __shfl_xor(sq, 16);
    sum += __shfl_xor(sum, 32); sq += __shfl_xor(sq, 32);
    if (quad == 0) {
      float mean = sum * (1.f / 256.f);
      float var  = sq * (1.f / 256.f) - mean * mean;
      smean[l] = mean; srs[l] = rsqrtf(var + 1e-5f);
    }
  }
  __syncthreads();
  {
    const float gg = gamma[tid], bb = beta[tid];
    const size_t base = ((size_t)b * LSEQ + l0) * DIMC + tid;
#pragma unroll 4
    for (int ll = 0; ll < 64; ++ll) {
      float v = (sx[tid][ll] - smean[ll]) * srs[ll] * gg + bb;
      xnb[base + (size_t)ll * DIMC] = f2bf(v);
    }
  }
}

// ---------------------------------------------------------------------------
// bf16 MFMA GEMM: C(f32) = A(bf16 [M][K]) * Bt(bf16 [N][K])^T.
// Tile: 128(M) x 64(N), BK=32. 4 waves 2x2, wave = 64x32 via 4x2 mfma.
#define GTM 128
#define GTN 64
#define GBK 32
__global__ __launch_bounds__(256) void gemm_bf16(const unsigned short* __restrict__ A,
                                                 const unsigned short* __restrict__ Bt,
                                                 float* __restrict__ C,
                                                 int M, int N, int K, int mode,
                                                 const float* __restrict__ X) {
  __shared__ unsigned short As[GTM][GBK];
  __shared__ unsigned short Bs[GTN][GBK];
  const int tid = threadIdx.x;
  const int lane = tid & 63, wave = tid >> 6;
  const int wm = wave >> 1, wn = wave & 1;
  const int quad = lane >> 4, l16 = lane & 15;
  const int m0 = blockIdx.y * GTM, n0 = blockIdx.x * GTN;

  f32x4 acc[4][2];
#pragma unroll
  for (int i = 0; i < 4; ++i)
#pragma unroll
    for (int j = 0; j < 2; ++j) acc[i][j] = (f32x4){0.f, 0.f, 0.f, 0.f};

  for (int k0 = 0; k0 < K; k0 += GBK) {
#pragma unroll
    for (int q = 0; q < 2; ++q) {
      int id = q * 256 + tid;
      int row = id >> 2, c = id & 3;
      uint4 v = *(const uint4*)(A + (size_t)(m0 + row) * K + k0 + c * 8);
      *(uint4*)&As[row][c * 8] = v;
    }
    {
      int row = tid >> 2, c = tid & 3;
      uint4 v = *(const uint4*)(Bt + (size_t)(n0 + row) * K + k0 + c * 8);
      *(uint4*)&Bs[row][c * 8] = v;
    }
    __syncthreads();
    short8 af[4], bfrag[2];
#pragma unroll
    for (int i = 0; i < 4; ++i)
      af[i] = *(const short8*)&As[wm * 64 + i * 16 + l16][quad * 8];
#pragma unroll
    for (int j = 0; j < 2; ++j)
      bfrag[j] = *(const short8*)&Bs[wn * 32 + j * 16 + l16][quad * 8];
#pragma unroll
    for (int i = 0; i < 4; ++i)
#pragma unroll
      for (int j = 0; j < 2; ++j)
        acc[i][j] = __builtin_amdgcn_mfma_f32_16x16x32_bf16(af[i], bfrag[j], acc[i][j], 0, 0, 0);
    __syncthreads();
  }

  if (mode == 0) {
#pragma unroll
    for (int i = 0; i < 4; ++i) {
      int rowb = wm * 64 + i * 16 + quad * 4;
#pragma unroll
      for (int j = 0; j < 2; ++j) {
        int n = n0 + wn * 32 + j * 16 + l16;
#pragma unroll
        for (int r = 0; r < 4; ++r)
          C[(size_t)(m0 + rowb + r) * N + n] = acc[i][j][r];
      }
    }
  } else {
#pragma unroll
    for (int i = 0; i < 4; ++i) {
      int m = m0 + wm * 64 + i * 16 + quad * 4;
      int b = m >> 10, l = m & 1023;
#pragma unroll
      for (int j = 0; j < 2; ++j) {
        int n = n0 + wn * 32 + j * 16 + l16;
        size_t o = (size_t)b * (DIMC * LSEQ) + (size_t)n * LSEQ + l;
        f32x4 xv = *(const f32x4*)(X + o);
        f32x4 rv = acc[i][j] + xv;
        *(f32x4*)(C + o) = rv;
      }
    }
  }
}

// ---------------------------------------------------------------------------
// Depthwise causal conv (k=4) + bias + SiLU; emits f32 u2 and bf16 u2b.
__global__ __launch_bounds__(256) void conv_silu(const float* __restrict__ xz,
                                                 const float* __restrict__ conv_w,
                                                 const float* __restrict__ conv_b,
                                                 float* __restrict__ u2,
                                                 unsigned short* __restrict__ u2b) {
  int idx = blockIdx.x * 256 + threadIdx.x;   // < MROWS*DI
  int c = idx & (DI - 1);
  int m = idx >> 9;
  int l = m & 1023;
  float acc = conv_b[c];
  const float* w = conv_w + c * 4;
#pragma unroll
  for (int k = 0; k < 4; ++k) {
    int lj = l - 3 + k;
    if (lj >= 0) acc = fmaf(xz[(size_t)(m - 3 + k) * 1024 + c], w[k], acc);
  }
  float sg = 1.f / (1.f + __expf(-acc));
  float v = acc * sg;
  u2[idx] = v;
  u2b[idx] = f2bf(v);
}

// ---------------------------------------------------------------------------
// xproj via MFMA: dbc64[M][64] = u2b[M][512] @ Wxpb[64][512]^T.
// m-tile 32, grid 256. B panel in LDS (+8 pad kills 16-way bank conflict).
__global__ __launch_bounds__(256) void xproj_mfma(const unsigned short* __restrict__ u2b,
                                                  const unsigned short* __restrict__ Wxpb,
                                                  float* __restrict__ dbc64) {
  __shared__ unsigned short Bs[64][512 + 8];
  const int m0 = blockIdx.x * 32;
  const int tid = threadIdx.x, lane = tid & 63, w = tid >> 6;
  const int quad = lane >> 4, l16 = lane & 15;
#pragma unroll
  for (int q = 0; q < 16; ++q) {
    int id = q * 256 + tid;          // 0..4095 chunks of 8 ushort
    int row = id >> 6, c8 = id & 63;
    *(uint4*)&Bs[row][c8 * 8] = *(const uint4*)(Wxpb + (size_t)row * 512 + c8 * 8);
  }
  __syncthreads();
  f32x4 acc[2];
  acc[0] = (f32x4){0.f, 0.f, 0.f, 0.f};
  acc[1] = (f32x4){0.f, 0.f, 0.f, 0.f};
#pragma unroll 4
  for (int k0 = 0; k0 < 512; k0 += 32) {
    short8 af0 = *(const short8*)(u2b + (size_t)(m0 + l16) * 512 + k0 + quad * 8);
    short8 af1 = *(const short8*)(u2b + (size_t)(m0 + 16 + l16) * 512 + k0 + quad * 8);
    short8 bf  = *(const short8*)&Bs[w * 16 + l16][k0 + quad * 8];
    acc[0] = __builtin_amdgcn_mfma_f32_16x16x32_bf16(af0, bf, acc[0], 0, 0, 0);
    acc[1] = __builtin_amdgcn_mfma_f32_16x16x32_bf16(af1, bf, acc[1], 0, 0, 0);
  }
#pragma unroll
  for (int i = 0; i < 2; ++i)
#pragma unroll
    for (int r = 0; r < 4; ++r)
      dbc64[(size_t)(m0 + i * 16 + quad * 4 + r) * 64 + w * 16 + l16] = acc[i][r];
}

// ---------------------------------------------------------------------------
// dt via MFMA: dtv[M][512] = softplus(dbc64[:,0:16] @ W_dt + b_dt).
// Wdtb [512][32] with k>=16 zeroed. m-tile 32, grid 256. No LDS.
__global__ __launch_bounds__(256) void dt_mfma(const float* __restrict__ dbc64,
                                               const unsigned short* __restrict__ Wdtb,
                                               const float* __restrict__ b_dt,
                                               float* __restrict__ dtv) {
  const int m0 = blockIdx.x * 32;
  const int tid = threadIdx.x, lane = tid & 63, w = tid >> 6;
  const int quad = lane >> 4, l16 = lane & 15;
  short8 af[2];
#pragma unroll
  for (int i = 0; i < 2; ++i) {
    const float* p = dbc64 + (size_t)(m0 + i * 16 + l16) * 64 + quad * 8;
    f32x4 v0 = *(const f32x4*)p;
    f32x4 v1 = *(const f32x4*)(p + 4);
    unsigned short tmp[8];
    tmp[0] = f2bf(v0[0]); tmp[1] = f2bf(v0[1]); tmp[2] = f2bf(v0[2]); tmp[3] = f2bf(v0[3]);
    tmp[4] = f2bf(v1[0]); tmp[5] = f2bf(v1[1]); tmp[6] = f2bf(v1[2]); tmp[7] = f2bf(v1[3]);
    af[i] = *(const short8*)tmp;
  }
#pragma unroll
  for (int jn = 0; jn < 8; ++jn) {
    const int n0 = w * 128 + jn * 16;
    short8 bf = *(const short8*)(Wdtb + (size_t)(n0 + l16) * 32 + quad * 8);
    f32x4 a0 = (f32x4){0.f, 0.f, 0.f, 0.f}, a1 = a0;
    a0 = __builtin_amdgcn_mfma_f32_16x16x32_bf16(af[0], bf, a0, 0, 0, 0);
    a1 = __builtin_amdgcn_mfma_f32_16x16x32_bf16(af[1], bf, a1, 0, 0, 0);
    const float bd = b_dt[n0 + l16];
#pragma unroll
    for (int r = 0; r < 4; ++r) {
      float v = a0[r] + bd;
      dtv[(size_t)(m0 + quad * 4 + r) * DI + n0 + l16] = (v > 20.f) ? v : log1pf(__expf(v));
      float v2 = a1[r] + bd;
      dtv[(size_t)(m0 + 16 + quad * 4 + r) * DI + n0 + l16] = (v2 > 20.f) ? v2 : log1pf(__expf(v2));
    }
  }
}

// ---------------------------------------------------------------------------
// Chunked selective scan. Pass 1: local scan from h=0 -> hend, sum dt.
__global__ __launch_bounds__(256) void scan_pass1(const float* __restrict__ dtv,
                                                  const float* __restrict__ u2,
                                                  const float* __restrict__ dbc64,
                                                  const float* __restrict__ A_log,
                                                  float* __restrict__ hend,
                                                  float* __restrict__ Ssum) {
  const int bb = blockIdx.x, dblk = blockIdx.y, cc = blockIdx.z;
  const int tid = threadIdx.x;
  const int di = tid >> 4, s = tid & 15;
  const int d = dblk * 16 + di;
  const float Ads = -__expf(A_log[d * DS + s]);

  __shared__ float sdt[CHUNK][16], su[CHUNK][16], sB[CHUNK][16];
  {
    const int t0 = cc * CHUNK;
#pragma unroll
    for (int q = 0; q < 4; ++q) {
      int lin = q * 256 + tid;
      int tt = lin >> 4, dd = lin & 15;
      size_t m = (size_t)bb * LSEQ + t0 + tt;
      sdt[tt][dd] = dtv[m * DI + dblk * 16 + dd];
      su [tt][dd] = u2 [m * DI + dblk * 16 + dd];
      sB [tt][dd] = dbc64[m * 64 + DTR + dd];
    }
  }
  __syncthreads();
  float h = 0.f, dtsum = 0.f;
  for (int tt = 0; tt < CHUNK; ++tt) {
    float dtt = sdt[tt][di];
    h = fmaf(__expf(dtt * Ads), h, dtt * su[tt][di] * sB[tt][s]);
    dtsum += dtt;
  }
  size_t ci = ((size_t)(bb * NC + cc) * DI + d);
  hend[ci * DS + s] = h;
  if (s == 0) Ssum[ci] = dtsum;
}

// Pass 2: sequential combine over chunks -> h_in per chunk.
__global__ __launch_bounds__(256) void scan_pass2(const float* __restrict__ A_log,
                                                  const float* __restrict__ hend,
                                                  const float* __restrict__ Ssum,
                                                  float* __restrict__ hin) {
  const int bb = blockIdx.x, dblk = blockIdx.y;
  const int tid = threadIdx.x;
  const int di = tid >> 4, s = tid & 15;
  const int d = dblk * 16 + di;
  const float Ads = -__expf(A_log[d * DS + s]);
  float h = 0.f;
  for (int cc = 0; cc < NC; ++cc) {
    size_t ci = ((size_t)(bb * NC + cc) * DI + d);
    hin[ci * DS + s] = h;
    h = fmaf(__expf(Ads * Ssum[ci]), h, hend[ci * DS + s]);
  }
}

// Pass 3: re-run each chunk from true h_in, fused gate epilogue -> yb (bf16).
__global__ __launch_bounds__(256) void scan_pass3(const float* __restrict__ dtv,
                                                  const float* __restrict__ u2,
                                                  const float* __restrict__ dbc64,
                                                  const float* __restrict__ xz,
                                                  const float* __restrict__ A_log,
                                                  const float* __restrict__ D_skip,
                                                  const float* __restrict__ hin,
                                                  unsigned short* __restrict__ yb) {
  const int bb = blockIdx.x, dblk = blockIdx.y, cc = blockIdx.z;
  const int tid = threadIdx.x;
  const int di = tid >> 4, s = tid & 15;
  const int d = dblk * 16 + di;
  const float Ads = -__expf(A_log[d * DS + s]);

  __shared__ float sdt[CHUNK][16], su[CHUNK][16], sB[CHUNK][16], sC[CHUNK][16],
                   sz[CHUNK][16], sy[CHUNK][16];
  const int t0 = cc * CHUNK;
#pragma unroll
  for (int q = 0; q < 4; ++q) {
    int lin = q * 256 + tid;
    int tt = lin >> 4, dd = lin & 15;
    size_t m = (size_t)bb * LSEQ + t0 + tt;
    sdt[tt][dd] = dtv[m * DI + dblk * 16 + dd];
    su [tt][dd] = u2 [m * DI + dblk * 16 + dd];
    sB [tt][dd] = dbc64[m * 64 + DTR + dd];
    sC [tt][dd] = dbc64[m * 64 + DTR + DS + dd];
    sz [tt][dd] = xz[m * 1024 + DI + dblk * 16 + dd];
  }
  __syncthreads();
  float h = hin[((size_t)(bb * NC + cc) * DI + d) * DS + s];
  for (int tt = 0; tt < CHUNK; ++tt) {
    float dtt = sdt[tt][di];
    h = fmaf(__expf(dtt * Ads), h, dtt * su[tt][di] * sB[tt][s]);
    float v = dpp_sum16(h * sC[tt][s]);
    if (s == 0) sy[tt][di] = v;
  }
  __syncthreads();
#pragma unroll
  for (int q = 0; q < 4; ++q) {
    int lin = q * 256 + tid;
    int tt = lin >> 4, dd = lin & 15;
    size_t m = (size_t)bb * LSEQ + t0 + tt;
    float yv = sy[tt][dd] + su[tt][dd] * D_skip[dblk * 16 + dd];
    float z = sz[tt][dd];
    yv *= z / (1.f + __expf(-z));
    yb[m * DI + dblk * 16 + dd] = f2bf(yv);
  }
}

// ---------------------------------------------------------------------------
extern "C" void kernel_launch(void* const* d_in, const int* in_sizes, int n_in,
                              void* d_out, int out_size, void* d_ws, size_t ws_size,
                              hipStream_t stream) {
  const float* x       = (const float*)d_in[0];
  const float* ln_g    = (const float*)d_in[1];
  const float* ln_b    = (const float*)d_in[2];
  const float* W_in    = (const float*)d_in[3];
  const float* conv_w  = (const float*)d_in[4];
  const float* conv_b  = (const float*)d_in[5];
  const float* W_xproj = (const float*)d_in[6];
  const float* W_dt    = (const float*)d_in[7];
  const float* b_dt    = (const float*)d_in[8];
  const float* A_log   = (const float*)d_in[9];
  const float* D_skip  = (const float*)d_in[10];
  const float* W_out   = (const float*)d_in[11];
  float* out = (float*)d_out;

  // Workspace layout
  float* ws    = (float*)d_ws;
  float* xz    = ws;                                    // 8,388,608 f
  float* u2    = xz   + (size_t)MROWS * 1024;           // 4,194,304 f
  float* dbc64 = u2   + (size_t)MROWS * DI;             //   524,288 f
  float* dtv   = dbc64 + (size_t)MROWS * 64;            // 4,194,304 f
  float* hend  = dtv  + (size_t)MROWS * DI;             // 1,048,576 f
  float* hin   = hend + (size_t)BATCH * NC * DI * DS;   // 1,048,576 f
  float* Ssum  = hin  + (size_t)BATCH * NC * DI * DS;   //    65,536 f
  unsigned short* u2b  = (unsigned short*)(Ssum + (size_t)BATCH * NC * DI);
  unsigned short* yb   = u2b + (size_t)MROWS * DI;      // 4,194,304 us
  unsigned short* xnb  = yb;   // alias: xnb dead before pass3 writes yb
  unsigned short* Wib  = yb  + (size_t)MROWS * DI;      // 262,144 us
  unsigned short* Wob  = Wib + (size_t)DIMC * 1024;     // 131,072 us
  unsigned short* Wxpb = Wob + (size_t)DI * DIMC;       //  32,768 us
  unsigned short* Wdtb = Wxpb + (size_t)64 * 512;       //  16,384 us

  // 0. weight prep
  wprep<<<dim3(1024 / 32, DIMC / 32), 256, 0, stream>>>(W_in, Wib, DIMC, 1024);
  wprep<<<dim3(DIMC / 32, DI / 32), 256, 0, stream>>>(W_out, Wob, DI, DIMC);
  wxprep<<<(64 * 512) / 256, 256, 0, stream>>>(W_xproj, Wxpb);
  wdtprep<<<(512 * 32) / 256, 256, 0, stream>>>(W_dt, Wdtb);

  // 1. LayerNorm -> bf16
  ln_kernel<<<dim3(LSEQ / 64, BATCH), 256, 0, stream>>>(x, ln_g, ln_b, xnb);

  // 2. xz = xn @ W_in   (8192x1024x256, bf16 MFMA)
  gemm_bf16<<<dim3(1024 / GTN, MROWS / GTM), 256, 0, stream>>>(
      xnb, Wib, xz, MROWS, 1024, DIMC, 0, nullptr);

  // 3. depthwise conv + SiLU -> u2 (f32) + u2b (bf16)
  conv_silu<<<(MROWS * DI) / 256, 256, 0, stream>>>(xz, conv_w, conv_b, u2, u2b);

  // 4. dbc64 = u2b @ W_xproj (MFMA, padded N=64)
  xproj_mfma<<<MROWS / 32, 256, 0, stream>>>(u2b, Wxpb, dbc64);

  // 5. dtv = softplus(dbc64[:,0:16] @ W_dt + b_dt) (MFMA)
  dt_mfma<<<MROWS / 32, 256, 0, stream>>>(dbc64, Wdtb, b_dt, dtv);

  // 6. chunked selective scan (pass3 emits gated bf16 yb directly)
  dim3 gp13(BATCH, DI / 16, NC);
  dim3 gp2(BATCH, DI / 16);
  scan_pass1<<<gp13, 256, 0, stream>>>(dtv, u2, dbc64, A_log, hend, Ssum);
  scan_pass2<<<gp2, 256, 0, stream>>>(A_log, hend, Ssum, hin);
  scan_pass3<<<gp13, 256, 0, stream>>>(dtv, u2, dbc64, xz, A_log, D_skip, hin, yb);

  // 7. out = yb @ W_out (transpose epilogue, +x residual)
  gemm_bf16<<<dim3(DIMC / GTN, MROWS / GTM), 256, 0, stream>>>(
      yb, Wob, out, MROWS, DIMC, DI, 1, x);
}

// Round 5
// 212.237 us; speedup vs baseline: 2.5624x; 1.0630x over previous
//
#include <hip/hip_runtime.h>
#include <hip/hip_bf16.h>
#include <math.h>

// Problem constants
#define DIMC   256      // DIM
#define DI     512      // D_INNER
#define DS     16       // D_STATE
#define DTR    16       // DT_RANK
#define NX     48       // DT_RANK + 2*D_STATE
#define BATCH  8
#define LSEQ   1024     // H*W
#define MROWS  8192     // BATCH*LSEQ
#define CHUNK  64
#define NC     (LSEQ / CHUNK)   // 16 chunks

typedef __attribute__((ext_vector_type(8))) short short8;
typedef __attribute__((ext_vector_type(4))) float f32x4;

__device__ __forceinline__ unsigned short f2bf(float v) {
  __hip_bfloat16 h = __float2bfloat16(v);
  return *reinterpret_cast<unsigned short*>(&h);
}

// Sum across the 16-lane group using DPP only (zero DS ops).
__device__ __forceinline__ float dpp_sum16(float v) {
  float t;
  t = __int_as_float(__builtin_amdgcn_mov_dpp(__float_as_int(v), 0xB1,  0xF, 0xF, true)); v += t; // ^1
  t = __int_as_float(__builtin_amdgcn_mov_dpp(__float_as_int(v), 0x4E,  0xF, 0xF, true)); v += t; // ^2
  t = __int_as_float(__builtin_amdgcn_mov_dpp(__float_as_int(v), 0x141, 0xF, 0xF, true)); v += t; // ^7 (row_half_mirror)
  t = __int_as_float(__builtin_amdgcn_mov_dpp(__float_as_int(v), 0x140, 0xF, 0xF, true)); v += t; // ^15 (row_mirror)
  return v;
}

// ---------------------------------------------------------------------------
// prep_all: all weight prep in ONE launch (branch on blockIdx.x).
//  blk [0,256):   Wib[n][k]  = bf16(W_in[k][n])   (K=256, N=1024) 32x8 tiles
//  blk [256,384): Wob[n][k]  = bf16(W_out[k][n])  (K=512, N=256)   8x16 tiles
//  blk [384,512): Wxpb[64][512], rows 48..63 zero
//  blk [512,576): Wdtb[512][32], cols k>=16 zero
__global__ __launch_bounds__(256) void prep_all(const float* __restrict__ W_in,
                                                const float* __restrict__ W_out,
                                                const float* __restrict__ W_xproj,
                                                const float* __restrict__ W_dt,
                                                unsigned short* __restrict__ Wib,
                                                unsigned short* __restrict__ Wob,
                                                unsigned short* __restrict__ Wxpb,
                                                unsigned short* __restrict__ Wdtb) {
  __shared__ float t[32][33];
  const int blk = blockIdx.x, tid = threadIdx.x;
  if (blk < 384) {
    const float* W; unsigned short* Wt; int K, N, bx, by;
    if (blk < 256) { W = W_in;  Wt = Wib; K = DIMC; N = 1024; bx = blk & 31; by = blk >> 5; }
    else           { W = W_out; Wt = Wob; K = DI;   N = DIMC; bx = (blk - 256) & 7; by = (blk - 256) >> 3; }
    int n0 = bx * 32, k0 = by * 32;
    int tx = tid & 31, ty = tid >> 5;
    for (int i = ty; i < 32; i += 8) t[i][tx] = W[(size_t)(k0 + i) * N + n0 + tx];
    __syncthreads();
    for (int i = ty; i < 32; i += 8)
      Wt[(size_t)(n0 + i) * K + k0 + tx] = f2bf(t[tx][i]);
  } else if (blk < 512) {
    int idx = (blk - 384) * 256 + tid;   // < 64*512
    int n = idx >> 9, k = idx & 511;
    Wxpb[idx] = (n < NX) ? f2bf(W_xproj[(size_t)k * NX + n]) : (unsigned short)0;
  } else {
    int idx = (blk - 512) * 256 + tid;   // < 512*32
    int n = idx >> 5, k = idx & 31;
    Wdtb[idx] = (k < DTR) ? f2bf(W_dt[(size_t)k * DI + n]) : (unsigned short)0;
  }
}

// ---------------------------------------------------------------------------
// LayerNorm, coalesced tile version. Block: 64 l x 256 c; grid (16, 8).
__global__ __launch_bounds__(256) void ln_kernel(const float* __restrict__ x,
                                                 const float* __restrict__ gamma,
                                                 const float* __restrict__ beta,
                                                 unsigned short* __restrict__ xnb) {
  __shared__ float sx[DIMC][67];
  __shared__ float smean[64], srs[64];
  const int b = blockIdx.y, l0 = blockIdx.x * 64;
  const int tid = threadIdx.x;
  {
    const int cbase = tid >> 2;
    const int lp = (tid & 3) * 16;
#pragma unroll
    for (int cg = 0; cg < 4; ++cg) {
      const int c = cg * 64 + cbase;
      const float* p = x + ((size_t)b * DIMC + c) * LSEQ + l0 + lp;
#pragma unroll
      for (int q = 0; q < 4; ++q) {
        float4 v = *(const float4*)(p + q * 4);
        sx[c][lp + q * 4 + 0] = v.x;
        sx[c][lp + q * 4 + 1] = v.y;
        sx[c][lp + q * 4 + 2] = v.z;
        sx[c][lp + q * 4 + 3] = v.w;
      }
    }
  }
  __syncthreads();
  {
    const int lane = tid & 63, w = tid >> 6;
    const int l = (w << 4) + (lane & 15);
    const int quad = lane >> 4;
    float sum = 0.f, sq = 0.f;
#pragma unroll 8
    for (int cc = 0; cc < 64; ++cc) {
      float v = sx[quad * 64 + cc][l];
      sum += v; sq += v * v;
    }
    sum += __shfl_xor(sum, 16); sq += __shfl_xor(sq, 16);
    sum += __shfl_xor(sum, 32); sq += __shfl_xor(sq, 32);
    if (quad == 0) {
      float mean = sum * (1.f / 256.f);
      float var  = sq * (1.f / 256.f) - mean * mean;
      smean[l] = mean; srs[l] = rsqrtf(var + 1e-5f);
    }
  }
  __syncthreads();
  {
    const float gg = gamma[tid], bb = beta[tid];
    const size_t base = ((size_t)b * LSEQ + l0) * DIMC + tid;
#pragma unroll 4
    for (int ll = 0; ll < 64; ++ll) {
      float v = (sx[tid][ll] - smean[ll]) * srs[ll] * gg + bb;
      xnb[base + (size_t)ll * DIMC] = f2bf(v);
    }
  }
}

// ---------------------------------------------------------------------------
// bf16 MFMA GEMM: C(f32) = A(bf16 [M][K]) * Bt(bf16 [N][K])^T.
#define GTM 128
#define GTN 64
#define GBK 32
__global__ __launch_bounds__(256) void gemm_bf16(const unsigned short* __restrict__ A,
                                                 const unsigned short* __restrict__ Bt,
                                                 float* __restrict__ C,
                                                 int M, int N, int K, int mode,
                                                 const float* __restrict__ X) {
  __shared__ unsigned short As[GTM][GBK];
  __shared__ unsigned short Bs[GTN][GBK];
  const int tid = threadIdx.x;
  const int lane = tid & 63, wave = tid >> 6;
  const int wm = wave >> 1, wn = wave & 1;
  const int quad = lane >> 4, l16 = lane & 15;
  const int m0 = blockIdx.y * GTM, n0 = blockIdx.x * GTN;

  f32x4 acc[4][2];
#pragma unroll
  for (int i = 0; i < 4; ++i)
#pragma unroll
    for (int j = 0; j < 2; ++j) acc[i][j] = (f32x4){0.f, 0.f, 0.f, 0.f};

  for (int k0 = 0; k0 < K; k0 += GBK) {
#pragma unroll
    for (int q = 0; q < 2; ++q) {
      int id = q * 256 + tid;
      int row = id >> 2, c = id & 3;
      uint4 v = *(const uint4*)(A + (size_t)(m0 + row) * K + k0 + c * 8);
      *(uint4*)&As[row][c * 8] = v;
    }
    {
      int row = tid >> 2, c = tid & 3;
      uint4 v = *(const uint4*)(Bt + (size_t)(n0 + row) * K + k0 + c * 8);
      *(uint4*)&Bs[row][c * 8] = v;
    }
    __syncthreads();
    short8 af[4], bfrag[2];
#pragma unroll
    for (int i = 0; i < 4; ++i)
      af[i] = *(const short8*)&As[wm * 64 + i * 16 + l16][quad * 8];
#pragma unroll
    for (int j = 0; j < 2; ++j)
      bfrag[j] = *(const short8*)&Bs[wn * 32 + j * 16 + l16][quad * 8];
#pragma unroll
    for (int i = 0; i < 4; ++i)
#pragma unroll
      for (int j = 0; j < 2; ++j)
        acc[i][j] = __builtin_amdgcn_mfma_f32_16x16x32_bf16(af[i], bfrag[j], acc[i][j], 0, 0, 0);
    __syncthreads();
  }

  if (mode == 0) {
#pragma unroll
    for (int i = 0; i < 4; ++i) {
      int rowb = wm * 64 + i * 16 + quad * 4;
#pragma unroll
      for (int j = 0; j < 2; ++j) {
        int n = n0 + wn * 32 + j * 16 + l16;
#pragma unroll
        for (int r = 0; r < 4; ++r)
          C[(size_t)(m0 + rowb + r) * N + n] = acc[i][j][r];
      }
    }
  } else {
#pragma unroll
    for (int i = 0; i < 4; ++i) {
      int m = m0 + wm * 64 + i * 16 + quad * 4;
      int b = m >> 10, l = m & 1023;
#pragma unroll
      for (int j = 0; j < 2; ++j) {
        int n = n0 + wn * 32 + j * 16 + l16;
        size_t o = (size_t)b * (DIMC * LSEQ) + (size_t)n * LSEQ + l;
        f32x4 xv = *(const f32x4*)(X + o);
        f32x4 rv = acc[i][j] + xv;
        *(f32x4*)(C + o) = rv;
      }
    }
  }
}

// ---------------------------------------------------------------------------
// Depthwise causal conv (k=4) + bias + SiLU, 2 channels/thread.
__global__ __launch_bounds__(256) void conv_silu(const float* __restrict__ xz,
                                                 const float* __restrict__ conv_w,
                                                 const float* __restrict__ conv_b,
                                                 float* __restrict__ u2,
                                                 unsigned int* __restrict__ u2b) {
  int idx = (blockIdx.x * 256 + threadIdx.x) * 2;   // < MROWS*DI
  int c = idx & (DI - 1);
  int m = idx >> 9;
  int l = m & 1023;
  float2 acc = *(const float2*)(conv_b + c);
  float4 w0 = *(const float4*)(conv_w + c * 4);
  float4 w1 = *(const float4*)(conv_w + c * 4 + 4);
  const float wa[4] = {w0.x, w0.y, w0.z, w0.w};
  const float wb[4] = {w1.x, w1.y, w1.z, w1.w};
#pragma unroll
  for (int k = 0; k < 4; ++k) {
    int lj = l - 3 + k;
    if (lj >= 0) {
      float2 v = *(const float2*)(xz + (size_t)(m - 3 + k) * 1024 + c);
      acc.x = fmaf(v.x, wa[k], acc.x);
      acc.y = fmaf(v.y, wb[k], acc.y);
    }
  }
  float vx = acc.x / (1.f + __expf(-acc.x));
  float vy = acc.y / (1.f + __expf(-acc.y));
  *(float2*)(u2 + idx) = make_float2(vx, vy);
  u2b[idx >> 1] = (unsigned int)f2bf(vx) | ((unsigned int)f2bf(vy) << 16);
}

// ---------------------------------------------------------------------------
// Fused xproj + dt (MFMA). m-tile 32, grid 256.
//   dbc64[M][64] = u2b[M][512] @ Wxpb[64][512]^T     (cols 0..47 meaningful)
//   dtv[M][512]  = softplus(dbc[:,0:16] @ W_dt + b_dt)
// dbc[:,0:32] is relayed to the dt stage through a padded LDS tile (bf16).
__global__ __launch_bounds__(256) void xproj_dt(const unsigned short* __restrict__ u2b,
                                                const unsigned short* __restrict__ Wxpb,
                                                const unsigned short* __restrict__ Wdtb,
                                                const float* __restrict__ b_dt,
                                                float* __restrict__ dbc64,
                                                float* __restrict__ dtv) {
  __shared__ unsigned short Bs[64][512 + 8];
  __shared__ unsigned short sdbc[32][40];   // +8 pad -> 2-way max on b128 reads
  const int m0 = blockIdx.x * 32;
  const int tid = threadIdx.x, lane = tid & 63, w = tid >> 6;
  const int quad = lane >> 4, l16 = lane & 15;
#pragma unroll
  for (int q = 0; q < 16; ++q) {
    int id = q * 256 + tid;
    int row = id >> 6, c8 = id & 63;
    *(uint4*)&Bs[row][c8 * 8] = *(const uint4*)(Wxpb + (size_t)row * 512 + c8 * 8);
  }
  __syncthreads();
  f32x4 acc[2];
  acc[0] = (f32x4){0.f, 0.f, 0.f, 0.f};
  acc[1] = (f32x4){0.f, 0.f, 0.f, 0.f};
#pragma unroll 4
  for (int k0 = 0; k0 < 512; k0 += 32) {
    short8 af0 = *(const short8*)(u2b + (size_t)(m0 + l16) * 512 + k0 + quad * 8);
    short8 af1 = *(const short8*)(u2b + (size_t)(m0 + 16 + l16) * 512 + k0 + quad * 8);
    short8 bf  = *(const short8*)&Bs[w * 16 + l16][k0 + quad * 8];
    acc[0] = __builtin_amdgcn_mfma_f32_16x16x32_bf16(af0, bf, acc[0], 0, 0, 0);
    acc[1] = __builtin_amdgcn_mfma_f32_16x16x32_bf16(af1, bf, acc[1], 0, 0, 0);
  }
#pragma unroll
  for (int i = 0; i < 2; ++i)
#pragma unroll
    for (int r = 0; r < 4; ++r)
      dbc64[(size_t)(m0 + i * 16 + quad * 4 + r) * 64 + w * 16 + l16] = acc[i][r];
  if (w < 2) {
#pragma unroll
    for (int i = 0; i < 2; ++i)
#pragma unroll
      for (int r = 0; r < 4; ++r)
        sdbc[i * 16 + quad * 4 + r][w * 16 + l16] = f2bf(acc[i][r]);
  }
  __syncthreads();
  // dt stage: A-frags straight from sdbc (A[m=l16][k=quad*8+j]).
  short8 af0 = *(const short8*)&sdbc[l16][quad * 8];
  short8 af1 = *(const short8*)&sdbc[16 + l16][quad * 8];
#pragma unroll
  for (int jn = 0; jn < 8; ++jn) {
    const int n0 = w * 128 + jn * 16;
    short8 bf = *(const short8*)(Wdtb + (size_t)(n0 + l16) * 32 + quad * 8);
    f32x4 a0 = (f32x4){0.f, 0.f, 0.f, 0.f}, a1 = a0;
    a0 = __builtin_amdgcn_mfma_f32_16x16x32_bf16(af0, bf, a0, 0, 0, 0);
    a1 = __builtin_amdgcn_mfma_f32_16x16x32_bf16(af1, bf, a1, 0, 0, 0);
    const float bd = b_dt[n0 + l16];
#pragma unroll
    for (int r = 0; r < 4; ++r) {
      float v = a0[r] + bd;
      dtv[(size_t)(m0 + quad * 4 + r) * DI + n0 + l16] = (v > 20.f) ? v : log1pf(__expf(v));
      float v2 = a1[r] + bd;
      dtv[(size_t)(m0 + 16 + quad * 4 + r) * DI + n0 + l16] = (v2 > 20.f) ? v2 : log1pf(__expf(v2));
    }
  }
}

// ---------------------------------------------------------------------------
// Chunked selective scan, float2-packed LDS.
// Pass 1: local scan from h=0 -> hend, sum dt.
__global__ __launch_bounds__(256) void scan_pass1(const float* __restrict__ dtv,
                                                  const float* __restrict__ u2,
                                                  const float* __restrict__ dbc64,
                                                  const float* __restrict__ A_log,
                                                  float* __restrict__ hend,
                                                  float* __restrict__ Ssum) {
  const int bb = blockIdx.x, dblk = blockIdx.y, cc = blockIdx.z;
  const int tid = threadIdx.x;
  const int di = tid >> 4, s = tid & 15;
  const int d = dblk * 16 + di;
  const float Ads = -__expf(A_log[d * DS + s]);

  __shared__ float2 sdu[CHUNK][16];   // (dt, u)
  __shared__ float  sB[CHUNK][16];
  {
    const int t0 = cc * CHUNK;
#pragma unroll
    for (int q = 0; q < 4; ++q) {
      int lin = q * 256 + tid;
      int tt = lin >> 4, dd = lin & 15;
      size_t m = (size_t)bb * LSEQ + t0 + tt;
      sdu[tt][dd] = make_float2(dtv[m * DI + dblk * 16 + dd], u2[m * DI + dblk * 16 + dd]);
      sB[tt][dd]  = dbc64[m * 64 + DTR + dd];
    }
  }
  __syncthreads();
  float h = 0.f, dtsum = 0.f;
#pragma unroll 4
  for (int tt = 0; tt < CHUNK; ++tt) {
    float2 du = sdu[tt][di];
    float Bv  = sB[tt][s];
    h = fmaf(__expf(du.x * Ads), h, du.x * du.y * Bv);
    dtsum += du.x;
  }
  size_t ci = ((size_t)(bb * NC + cc) * DI + d);
  hend[ci * DS + s] = h;
  if (s == 0) Ssum[ci] = dtsum;
}

// Pass 2: sequential combine over chunks -> h_in per chunk.
__global__ __launch_bounds__(256) void scan_pass2(const float* __restrict__ A_log,
                                                  const float* __restrict__ hend,
                                                  const float* __restrict__ Ssum,
                                                  float* __restrict__ hin) {
  const int bb = blockIdx.x, dblk = blockIdx.y;
  const int tid = threadIdx.x;
  const int di = tid >> 4, s = tid & 15;
  const int d = dblk * 16 + di;
  const float Ads = -__expf(A_log[d * DS + s]);
  float h = 0.f;
  for (int cc = 0; cc < NC; ++cc) {
    size_t ci = ((size_t)(bb * NC + cc) * DI + d);
    hin[ci * DS + s] = h;
    h = fmaf(__expf(Ads * Ssum[ci]), h, hend[ci * DS + s]);
  }
}

// Pass 3: re-run each chunk from true h_in, fused gate epilogue -> yb (bf16).
__global__ __launch_bounds__(256) void scan_pass3(const float* __restrict__ dtv,
                                                  const float* __restrict__ u2,
                                                  const float* __restrict__ dbc64,
                                                  const float* __restrict__ xz,
                                                  const float* __restrict__ A_log,
                                                  const float* __restrict__ D_skip,
                                                  const float* __restrict__ hin,
                                                  unsigned short* __restrict__ yb) {
  const int bb = blockIdx.x, dblk = blockIdx.y, cc = blockIdx.z;
  const int tid = threadIdx.x;
  const int di = tid >> 4, s = tid & 15;
  const int d = dblk * 16 + di;
  const float Ads = -__expf(A_log[d * DS + s]);

  __shared__ float2 sdu[CHUNK][16];   // (dt, u)
  __shared__ float2 sBC[CHUNK][16];   // (B, C)
  __shared__ float  sz[CHUNK][16], sy[CHUNK][16];
  const int t0 = cc * CHUNK;
#pragma unroll
  for (int q = 0; q < 4; ++q) {
    int lin = q * 256 + tid;
    int tt = lin >> 4, dd = lin & 15;
    size_t m = (size_t)bb * LSEQ + t0 + tt;
    sdu[tt][dd] = make_float2(dtv[m * DI + dblk * 16 + dd], u2[m * DI + dblk * 16 + dd]);
    sBC[tt][dd] = make_float2(dbc64[m * 64 + DTR + dd], dbc64[m * 64 + DTR + DS + dd]);
    sz [tt][dd] = xz[m * 1024 + DI + dblk * 16 + dd];
  }
  __syncthreads();
  float h = hin[((size_t)(bb * NC + cc) * DI + d) * DS + s];
#pragma unroll 4
  for (int tt = 0; tt < CHUNK; ++tt) {
    float2 du = sdu[tt][di];
    float2 bc = sBC[tt][s];
    h = fmaf(__expf(du.x * Ads), h, du.x * du.y * bc.x);
    float v = dpp_sum16(h * bc.y);
    if (s == 0) sy[tt][di] = v;
  }
  __syncthreads();
#pragma unroll
  for (int q = 0; q < 4; ++q) {
    int lin = q * 256 + tid;
    int tt = lin >> 4, dd = lin & 15;
    size_t m = (size_t)bb * LSEQ + t0 + tt;
    float yv = sy[tt][dd] + sdu[tt][dd].y * D_skip[dblk * 16 + dd];
    float z = sz[tt][dd];
    yv *= z / (1.f + __expf(-z));
    yb[m * DI + dblk * 16 + dd] = f2bf(yv);
  }
}

// ---------------------------------------------------------------------------
extern "C" void kernel_launch(void* const* d_in, const int* in_sizes, int n_in,
                              void* d_out, int out_size, void* d_ws, size_t ws_size,
                              hipStream_t stream) {
  const float* x       = (const float*)d_in[0];
  const float* ln_g    = (const float*)d_in[1];
  const float* ln_b    = (const float*)d_in[2];
  const float* W_in    = (const float*)d_in[3];
  const float* conv_w  = (const float*)d_in[4];
  const float* conv_b  = (const float*)d_in[5];
  const float* W_xproj = (const float*)d_in[6];
  const float* W_dt    = (const float*)d_in[7];
  const float* b_dt    = (const float*)d_in[8];
  const float* A_log   = (const float*)d_in[9];
  const float* D_skip  = (const float*)d_in[10];
  const float* W_out   = (const float*)d_in[11];
  float* out = (float*)d_out;

  // Workspace layout
  float* ws    = (float*)d_ws;
  float* xz    = ws;                                    // 8,388,608 f
  float* u2    = xz   + (size_t)MROWS * 1024;           // 4,194,304 f
  float* dbc64 = u2   + (size_t)MROWS * DI;             //   524,288 f
  float* dtv   = dbc64 + (size_t)MROWS * 64;            // 4,194,304 f
  float* hend  = dtv  + (size_t)MROWS * DI;             // 1,048,576 f
  float* hin   = hend + (size_t)BATCH * NC * DI * DS;   // 1,048,576 f
  float* Ssum  = hin  + (size_t)BATCH * NC * DI * DS;   //    65,536 f
  unsigned short* u2b  = (unsigned short*)(Ssum + (size_t)BATCH * NC * DI);
  unsigned short* yb   = u2b + (size_t)MROWS * DI;      // 4,194,304 us
  unsigned short* xnb  = yb;   // alias: xnb dead before pass3 writes yb
  unsigned short* Wib  = yb  + (size_t)MROWS * DI;      // 262,144 us
  unsigned short* Wob  = Wib + (size_t)DIMC * 1024;     // 131,072 us
  unsigned short* Wxpb = Wob + (size_t)DI * DIMC;       //  32,768 us
  unsigned short* Wdtb = Wxpb + (size_t)64 * 512;       //  16,384 us

  // 0. all weight prep in one launch
  prep_all<<<576, 256, 0, stream>>>(W_in, W_out, W_xproj, W_dt, Wib, Wob, Wxpb, Wdtb);

  // 1. LayerNorm -> bf16
  ln_kernel<<<dim3(LSEQ / 64, BATCH), 256, 0, stream>>>(x, ln_g, ln_b, xnb);

  // 2. xz = xn @ W_in   (8192x1024x256, bf16 MFMA)
  gemm_bf16<<<dim3(1024 / GTN, MROWS / GTM), 256, 0, stream>>>(
      xnb, Wib, xz, MROWS, 1024, DIMC, 0, nullptr);

  // 3. depthwise conv + SiLU -> u2 (f32) + u2b (bf16), 2 ch/thread
  conv_silu<<<(MROWS * DI) / 512, 256, 0, stream>>>(xz, conv_w, conv_b, u2,
                                                    (unsigned int*)u2b);

  // 4+5. fused: dbc64 = u2b @ W_xproj ; dtv = softplus(dbc @ W_dt + b_dt)
  xproj_dt<<<MROWS / 32, 256, 0, stream>>>(u2b, Wxpb, Wdtb, b_dt, dbc64, dtv);

  // 6. chunked selective scan (pass3 emits gated bf16 yb directly)
  dim3 gp13(BATCH, DI / 16, NC);
  dim3 gp2(BATCH, DI / 16);
  scan_pass1<<<gp13, 256, 0, stream>>>(dtv, u2, dbc64, A_log, hend, Ssum);
  scan_pass2<<<gp2, 256, 0, stream>>>(A_log, hend, Ssum, hin);
  scan_pass3<<<gp13, 256, 0, stream>>>(dtv, u2, dbc64, xz, A_log, D_skip, hin, yb);

  // 7. out = yb @ W_out (transpose epilogue, +x residual)
  gemm_bf16<<<dim3(DIMC / GTN, MROWS / GTM), 256, 0, stream>>>(
      yb, Wob, out, MROWS, DIMC, DI, 1, x);
}